// Round 5
// baseline (6684.537 us; speedup 1.0000x reference)
//
#include <hip/hip_runtime.h>

// LSTM scan, B=64, T=16384, H=32, I=O=1, fp32.
// ONE WAVE PER BATCH PAIR (32 blocks x 64 threads). Pure latency problem:
// wall time = T x per-step dependence-chain length of one wave's stream.
//
// Round-5 structure: lane l = unit j (l&31) of batch (2*blockIdx + l>>5).
// Each lane computes ALL FOUR gates for its unit (lane-local cell update:
// no cross-half exchange, no permlane hazards). Two batches share the wave,
// so every latency bubble of one chain is fillable by the other chain's
// instructions -- 2x ILP on the same critical path we were already paying.
//
// h_{t-1} broadcast: ds_bpermute_b32 (single-pass register pull on the DS
// pipe; source lane = half*32+k, so each half pulls its own batch's h).
// The x/bias contribution is added AFTER the matvec so its bpermute's
// latency hides under the 64-pk_fma block.
//
// Weights pre-scaled by -log2(e) (sigmoid rows) / -2log2(e) (tanh row):
// sigmoid(s) = rcp(1+exp2(s')) and tanh(s) = 2*rcp(1+exp2(s'')) - 1 with
// zero extra muls on the chain.

#define HID 32
#define CHUNK 32

typedef float f2 __attribute__((ext_vector_type(2)));
typedef float f4 __attribute__((ext_vector_type(4)));

__device__ __forceinline__ float bperm(int byte_addr, float v) {
    return __int_as_float(__builtin_amdgcn_ds_bpermute(byte_addr, __float_as_int(v)));
}

__global__ __launch_bounds__(64, 1)
void lstm_pair_scan(const float* __restrict__ x,
                    const float* __restrict__ W_ih,
                    const float* __restrict__ W_hh,
                    const float* __restrict__ b_ih,
                    const float* __restrict__ b_hh,
                    const float* __restrict__ W_lin,
                    const float* __restrict__ b_lin,
                    float* __restrict__ out,
                    int T) {
    __shared__ float h_hist[CHUNK][65];   // row stride 65: epilogue conflict-free

    const int lane = threadIdx.x;
    const int j    = lane & 31;     // hidden unit
    const int half = lane >> 5;     // which batch of the pair
    const int b    = (blockIdx.x << 1) + half;

    const float S1 = -1.44269504088896340736f;  // -log2(e)      (sigmoid)
    const float S2 = -2.88539008177792681472f;  // -2 log2(e)    (tanh)

    // Per-lane weights: W_hh rows j (i), 32+j (f), 64+j (g), 96+j (o),
    // pre-scaled so the activation is rcp(1+exp2(acc)) directly.
    f2 wi[16], wf[16], wg[16], wo[16];
    {
        const f4* Ri = (const f4*)(W_hh + (0  + j) * HID);
        const f4* Rf = (const f4*)(W_hh + (32 + j) * HID);
        const f4* Rg = (const f4*)(W_hh + (64 + j) * HID);
        const f4* Ro = (const f4*)(W_hh + (96 + j) * HID);
#pragma unroll
        for (int m = 0; m < 8; ++m) {
            f4 v;
            v = Ri[m]; wi[2*m] = {v.x*S1, v.y*S1}; wi[2*m+1] = {v.z*S1, v.w*S1};
            v = Rf[m]; wf[2*m] = {v.x*S1, v.y*S1}; wf[2*m+1] = {v.z*S1, v.w*S1};
            v = Rg[m]; wg[2*m] = {v.x*S2, v.y*S2}; wg[2*m+1] = {v.z*S2, v.w*S2};
            v = Ro[m]; wo[2*m] = {v.x*S1, v.y*S1}; wo[2*m+1] = {v.z*S1, v.w*S1};
        }
    }
    const float wih_i = W_ih[j]      * S1, bi = (b_ih[j]      + b_hh[j])      * S1;
    const float wih_f = W_ih[32 + j] * S1, bf = (b_ih[32 + j] + b_hh[32 + j]) * S1;
    const float wih_g = W_ih[64 + j] * S2, bg = (b_ih[64 + j] + b_hh[64 + j]) * S2;
    const float wih_o = W_ih[96 + j] * S1, bo = (b_ih[96 + j] + b_hh[96 + j]) * S1;
    const float blin  = b_lin[0];

    const int vbase = half << 7;    // bpermute byte base: source lane half*32

    float c = 0.0f;
    float h = 0.0f;

    const float* xb = x   + (size_t)b * T;
    float*       ob = out + (size_t)b * T;

    float xv = xb[j];               // lane j holds x[b][t0+j] for current chunk

    for (int t0 = 0; t0 < T; t0 += CHUNK) {
        int t0n = t0 + CHUNK; if (t0n >= T) t0n = 0;
        float xv_next = xb[t0n + j];

#pragma unroll 4
        for (int tt = 0; tt < CHUNK; ++tt) {
            // x_t for my batch: issued first, consumed ~130 cyc later.
            const float xk = bperm(vbase + 4 * tt, xv);

            f2 ai = {bi, 0.0f}, af2 = {bf, 0.0f}, ag = {bg, 0.0f}, ao = {bo, 0.0f};
            // Matvec: h pulled pairwise via bpermute, 4 independent 16-deep
            // FMA chains (issue-bound, fully overlapped across the 2 batches).
#pragma unroll
            for (int m = 0; m < 16; ++m) {
                const float h0 = bperm(vbase + 8 * m,     h);
                const float h1 = bperm(vbase + 8 * m + 4, h);
                const f2 hm = {h0, h1};
                ai  = __builtin_elementwise_fma(wi[m], hm, ai);
                af2 = __builtin_elementwise_fma(wf[m], hm, af2);
                ag  = __builtin_elementwise_fma(wg[m], hm, ag);
                ao  = __builtin_elementwise_fma(wo[m], hm, ao);
            }
            // Fold the x contribution in at the end (hides xk's DS latency).
            const float gi = __builtin_fmaf(xk, wih_i, ai.x  + ai.y);
            const float gf = __builtin_fmaf(xk, wih_f, af2.x + af2.y);
            const float gg = __builtin_fmaf(xk, wih_g, ag.x  + ag.y);
            const float go = __builtin_fmaf(xk, wih_o, ao.x  + ao.y);

            const float ii = __builtin_amdgcn_rcpf(1.0f + __builtin_amdgcn_exp2f(gi));
            const float ff = __builtin_amdgcn_rcpf(1.0f + __builtin_amdgcn_exp2f(gf));
            const float g_ = __builtin_fmaf(2.0f,
                               __builtin_amdgcn_rcpf(1.0f + __builtin_amdgcn_exp2f(gg)), -1.0f);
            const float oo = __builtin_amdgcn_rcpf(1.0f + __builtin_amdgcn_exp2f(go));

            c = __builtin_fmaf(ff, c, ii * g_);
            const float th = __builtin_fmaf(2.0f,
                               __builtin_amdgcn_rcpf(1.0f + __builtin_amdgcn_exp2f(c * S2)), -1.0f);
            h = oo * th;

            h_hist[tt][lane] = h;   // col l = unit j of batch half
        }

        // ---- epilogue: out[b][t0+t'] = x + W_lin . h_t' + b_lin, t' = j.
        // Lane l reads row j, cols half*32+k: stride-65 rows -> within a
        // half all banks distinct; across halves 2-way (free).
        {
            float facc = 0.0f;
#pragma unroll
            for (int k = 0; k < 32; ++k)
                facc = __builtin_fmaf(W_lin[k], h_hist[j][(half << 5) + k], facc);
            ob[t0 + j] = xv + facc + blin;
        }

        xv = xv_next;
    }
}

extern "C" void kernel_launch(void* const* d_in, const int* in_sizes, int n_in,
                              void* d_out, int out_size, void* d_ws, size_t ws_size,
                              hipStream_t stream) {
    const float* x     = (const float*)d_in[0];
    const float* W_ih  = (const float*)d_in[1];
    const float* W_hh  = (const float*)d_in[2];
    const float* b_ih  = (const float*)d_in[3];
    const float* b_hh  = (const float*)d_in[4];
    const float* W_lin = (const float*)d_in[5];
    const float* b_lin = (const float*)d_in[6];
    float* out = (float*)d_out;

    const int B = 64;
    const int T = in_sizes[0] / B;   // 16384

    dim3 grid(B / 2);                // one wave per batch pair
    dim3 block(64);
    lstm_pair_scan<<<grid, block, 0, stream>>>(x, W_ih, W_hh, b_ih, b_hh,
                                               W_lin, b_lin, out, T);
}

// Round 6
// 5981.339 us; speedup vs baseline: 1.1176x; 1.1176x over previous
//
#include <hip/hip_runtime.h>

// LSTM scan, B=64, T=16384, H=32, I=O=1, fp32 in/out.
// ONE WAVE PER BATCH (64 blocks x 64 threads). Pure latency problem: wall
// time = T x per-step dependence chain of a single wave. Round-6 changes
// vs round 4 (3276 us, 472 cyc/step):
//   - matvec via v_dot2_f32_f16: h converted to f16 once per step, readlaned
//     as 16-bit patterns, packed pairwise with SALU integer ops (parallel
//     pipe), consumed as a SINGLE 32-bit SGPR operand per dot. Removes the
//     aligned-SGPR-pair materialization risk of v_pk_fma_f32 f2 operands.
//   - 4-way split accumulators: dependent chain depth 16 -> 4.
//   - weights/biases pre-scaled by -log2(e) (sigmoid) / -2log2(e) (tanh):
//     activations are rcp(1+exp2(acc)) with no pre-multiply.
// Round-5 lesson (6.7 ms): NO DS-pipe ops (bpermute/shfl/swizzle) on the
// chain -- readlane only. Round-3 lesson: permlane32_swap only via builtin.
//
// Lane mapping: j = lane&31, half = lane>>5.
//   A-lanes (half=0): gates i (row j)    and g (row 64+j)
//   B-lanes (half=1): gates f (row 32+j) and o (row 96+j)
// c,h valid in B-lanes; A-lanes compute bounded garbage (i-contraction).

#define HID 32
#define CHUNK 32

typedef _Float16 f16x2 __attribute__((ext_vector_type(2)));
typedef unsigned int u32x2 __attribute__((ext_vector_type(2)));

#if defined(__has_builtin)
#if __has_builtin(__builtin_amdgcn_permlane32_swap)
#define HAVE_PLSWAP 1
#endif
#if __has_builtin(__builtin_amdgcn_fdot2)
#define HAVE_FDOT2 1
#endif
#endif

__device__ __forceinline__ float rl(float v, int lane) {
    return __int_as_float(__builtin_amdgcn_readlane(__float_as_int(v), lane));
}
__device__ __forceinline__ unsigned rlu(unsigned v, int lane) {
    return (unsigned)__builtin_amdgcn_readlane((int)v, lane);
}

__device__ __forceinline__ float fdot2(f16x2 a, f16x2 b, float c) {
#ifdef HAVE_FDOT2
    return __builtin_amdgcn_fdot2(a, b, c, false);
#else
    return __builtin_fmaf((float)a.x, (float)b.x,
           __builtin_fmaf((float)a.y, (float)b.y, c));
#endif
}

// Exchange p across wave halves (exact, orientation-independent, VALU-only).
__device__ __forceinline__ float cross_half(float p) {
#ifdef HAVE_PLSWAP
    const unsigned pu = __float_as_uint(p);
    u32x2 r = __builtin_amdgcn_permlane32_swap(pu, pu, false, false);
    return __uint_as_float(r[0] ^ r[1] ^ pu);
#else
    return __shfl_xor(p, 32, 64);
#endif
}

__global__ __launch_bounds__(64, 1)
void lstm_wave_scan(const float* __restrict__ x,
                    const float* __restrict__ W_ih,
                    const float* __restrict__ W_hh,
                    const float* __restrict__ b_ih,
                    const float* __restrict__ b_hh,
                    const float* __restrict__ W_lin,
                    const float* __restrict__ b_lin,
                    float* __restrict__ out,
                    int T) {
    __shared__ float h_hist[CHUNK][65];   // row stride 65: epilogue conflict-free

    const int lane = threadIdx.x;
    const int j    = lane & 31;
    const int half = lane >> 5;
    const int b    = blockIdx.x;

    const int row1 = j + (half << 5);         // A: i-row j     B: f-row 32+j
    const int row2 = 64 + j + (half << 5);    // A: g-row 64+j  B: o-row 96+j

    const float S1 = -1.44269504088896340736f;   // -log2(e)   (sigmoid rows)
    const float S2 = -2.88539008177792681472f;   // -2 log2(e) (tanh row)
    const float sc2 = half ? S1 : S2;            // row2: A is tanh, B is sigmoid

    // Pre-scaled f16-packed weights: w[m] = {W[row][2m], W[row][2m+1]} * scale
    f16x2 w1[16], w2[16];
#pragma unroll
    for (int m = 0; m < 16; ++m) {
        w1[m] = { (_Float16)(W_hh[row1 * HID + 2*m]     * S1),
                  (_Float16)(W_hh[row1 * HID + 2*m + 1] * S1) };
        w2[m] = { (_Float16)(W_hh[row2 * HID + 2*m]     * sc2),
                  (_Float16)(W_hh[row2 * HID + 2*m + 1] * sc2) };
    }
    const float wih1 = W_ih[row1] * S1,  bb1 = (b_ih[row1] + b_hh[row1]) * S1;
    const float wih2 = W_ih[row2] * sc2, bb2 = (b_ih[row2] + b_hh[row2]) * sc2;

    // act2(v) = pb * rcp(1 + exp2(v)) + pc : A-lanes tanh, B-lanes sigmoid
    const float pb = half ? 1.0f : 2.0f;
    const float pc = half ? 0.0f : -1.0f;

    const float blin = b_lin[0];

    float c = 0.0f;          // B-lanes: cell state
    unsigned h16u = 0;       // f16 bit pattern of h_{t-1} (lane 32+k = unit k)
    float h = 0.0f;

    const float* xb = x   + (size_t)b * T;
    float*       ob = out + (size_t)b * T;

    float xv = xb[j];

    for (int t0 = 0; t0 < T; t0 += CHUNK) {
        int t0n = t0 + CHUNK; if (t0n >= T) t0n = 0;
        float xv_next = xb[t0n + j];

#pragma unroll
        for (int tt = 0; tt < CHUNK; ++tt) {
            const float sx = rl(xv, tt);  // wave-uniform x_t (off-chain)

            // 4-way split accumulators; x/bias folded into partial 0.
            float a1p0 = __builtin_fmaf(sx, wih1, bb1), a1p1 = 0.f, a1p2 = 0.f, a1p3 = 0.f;
            float a2p0 = __builtin_fmaf(sx, wih2, bb2), a2p1 = 0.f, a2p2 = 0.f, a2p3 = 0.f;

#pragma unroll
            for (int m = 0; m < 4; ++m) {
                // Readlane h-f16 bits from B-lanes, pack pairs on the SALU,
                // feed v_dot2_f32_f16 with a single-SGPR packed operand.
                unsigned l0 = rlu(h16u, 32 + 8*m    ), l1 = rlu(h16u, 33 + 8*m);
                unsigned l2 = rlu(h16u, 34 + 8*m    ), l3 = rlu(h16u, 35 + 8*m);
                unsigned l4 = rlu(h16u, 36 + 8*m    ), l5 = rlu(h16u, 37 + 8*m);
                unsigned l6 = rlu(h16u, 38 + 8*m    ), l7 = rlu(h16u, 39 + 8*m);
                unsigned p0 = (l0 & 0xffffu) | (l1 << 16);   // s_pack_ll
                unsigned p1 = (l2 & 0xffffu) | (l3 << 16);
                unsigned p2 = (l4 & 0xffffu) | (l5 << 16);
                unsigned p3 = (l6 & 0xffffu) | (l7 << 16);
                f16x2 h0 = __builtin_bit_cast(f16x2, p0);
                f16x2 h1 = __builtin_bit_cast(f16x2, p1);
                f16x2 h2 = __builtin_bit_cast(f16x2, p2);
                f16x2 h3 = __builtin_bit_cast(f16x2, p3);
                a1p0 = fdot2(w1[4*m + 0], h0, a1p0);
                a2p0 = fdot2(w2[4*m + 0], h0, a2p0);
                a1p1 = fdot2(w1[4*m + 1], h1, a1p1);
                a2p1 = fdot2(w2[4*m + 1], h1, a2p1);
                a1p2 = fdot2(w1[4*m + 2], h2, a1p2);
                a2p2 = fdot2(w2[4*m + 2], h2, a2p2);
                a1p3 = fdot2(w1[4*m + 3], h3, a1p3);
                a2p3 = fdot2(w2[4*m + 3], h3, a2p3);
            }
            const float g1 = (a1p0 + a1p1) + (a1p2 + a1p3);  // A: i-pre  B: f-pre
            const float g2 = (a2p0 + a2p1) + (a2p2 + a2p3);  // A: g-pre  B: o-pre

            // Activations (weights pre-scaled: no multiply before exp2).
            const float a1 = __builtin_amdgcn_rcpf(1.0f + __builtin_amdgcn_exp2f(g1));
            const float a2 = __builtin_fmaf(pb,
                               __builtin_amdgcn_rcpf(1.0f + __builtin_amdgcn_exp2f(g2)), pc);

            const float p = a1 * a2;            // A: i*g     B: f*o
            const float q = cross_half(p);      // A: f*o     B: i*g

            c = __builtin_fmaf(a1, c, q);       // B: f*c + i*g
            const float e = __builtin_amdgcn_exp2f(c * S2);
            const float th = __builtin_fmaf(2.0f, __builtin_amdgcn_rcpf(1.0f + e), -1.0f);
            h = a2 * th;                        // B: o*tanh(c)

            h16u = (unsigned)(unsigned short)__builtin_bit_cast(unsigned short, (_Float16)h);
            h_hist[tt][lane] = h;               // cols 32..63 hold the real h
        }

        // ---- epilogue: out[b][t0+t'] = x + W_lin . h_t' + b_lin, t' = j
        {
            float facc = 0.0f;
#pragma unroll
            for (int k = 0; k < 32; ++k)
                facc = __builtin_fmaf(W_lin[k], h_hist[j][32 + k], facc);
            if (half == 0)
                ob[t0 + j] = xv + facc + blin;
        }

        xv = xv_next;
    }
}

extern "C" void kernel_launch(void* const* d_in, const int* in_sizes, int n_in,
                              void* d_out, int out_size, void* d_ws, size_t ws_size,
                              hipStream_t stream) {
    const float* x     = (const float*)d_in[0];
    const float* W_ih  = (const float*)d_in[1];
    const float* W_hh  = (const float*)d_in[2];
    const float* b_ih  = (const float*)d_in[3];
    const float* b_hh  = (const float*)d_in[4];
    const float* W_lin = (const float*)d_in[5];
    const float* b_lin = (const float*)d_in[6];
    float* out = (float*)d_out;

    const int B = 64;
    const int T = in_sizes[0] / B;   // 16384

    dim3 grid(B);                    // one wave per batch
    dim3 block(64);
    lstm_wave_scan<<<grid, block, 0, stream>>>(x, W_ih, W_hh, b_ih, b_hh,
                                               W_lin, b_lin, out, T);
}

// Round 8
// 3711.021 us; speedup vs baseline: 1.8013x; 1.6118x over previous
//
#include <hip/hip_runtime.h>

// LSTM scan, B=64, T=16384, H=32, I=O=1, fp32 in/out.
// ONE WAVE PER BATCH (64 blocks x 64 threads). Latency-bound serial scan:
// wall time = T x per-step dependence chain of one wave.
//
// Round-8 = round-7 with the cvt_pkrtz type fixed (builtin returns
// __fp16-vector; bit_cast to unsigned instead of initializing f16x2).
// Structure: h -> f16 pair-packed IN-REGISTER via DPP quad_perm +
// v_cvt_pkrtz (VALU-only), 16 readlanes of packed pairs feed
// v_dot2_f32_f16 whose h operand is a single 32-bit SGPR. Weights
// pre-scaled by -log2(e)/-2log2(e). 4-way split accumulators.
//
// Hard lessons encoded here:
//   r1/r5: DS-pipe ops (shfl/bpermute) on the chain are poison (~100+ cyc).
//   r3:    permlane32_swap ONLY via the builtin (hazard wait-states).
//   r6:    readlane results must NOT be consumed by SALU ops.
//
// Lane mapping: j = lane&31, half = lane>>5.
//   A-lanes (half=0): gates i (row j)    and g (row 64+j)
//   B-lanes (half=1): gates f (row 32+j) and o (row 96+j)
// c,h valid in B-lanes; A-lanes compute bounded garbage (sigmoid-contraction).

#define HID 32
#define CHUNK 32

typedef _Float16 f16x2 __attribute__((ext_vector_type(2)));
typedef float f2 __attribute__((ext_vector_type(2)));
typedef unsigned int u32x2 __attribute__((ext_vector_type(2)));

#if defined(__has_builtin)
#if __has_builtin(__builtin_amdgcn_permlane32_swap)
#define HAVE_PLSWAP 1
#endif
#if __has_builtin(__builtin_amdgcn_fdot2)
#define HAVE_FDOT2 1
#endif
#endif

__device__ __forceinline__ float rl(float v, int lane) {
    return __int_as_float(__builtin_amdgcn_readlane(__float_as_int(v), lane));
}
__device__ __forceinline__ unsigned rlu(unsigned v, int lane) {
    return (unsigned)__builtin_amdgcn_readlane((int)v, lane);
}

// Exchange p across wave halves (exact, orientation-independent, VALU-only).
__device__ __forceinline__ float cross_half(float p) {
#ifdef HAVE_PLSWAP
    const unsigned pu = __float_as_uint(p);
    u32x2 r = __builtin_amdgcn_permlane32_swap(pu, pu, false, false);
    return __uint_as_float(r[0] ^ r[1] ^ pu);
#else
    return __shfl_xor(p, 32, 64);
#endif
}

// Pack {h(this lane), h(lane^1)} into one 32-bit f16x2 word, VALU-only.
__device__ __forceinline__ unsigned pack_pair_f16(float h) {
    const int hn_i = __builtin_amdgcn_update_dpp(
        __float_as_int(h), __float_as_int(h), 0xB1 /*quad_perm 1,0,3,2*/,
        0xF, 0xF, false);
    const float hn = __int_as_float(hn_i);
#if defined(__has_builtin) && __has_builtin(__builtin_amdgcn_cvt_pkrtz)
    return __builtin_bit_cast(unsigned, __builtin_amdgcn_cvt_pkrtz(h, hn));
#else
    f16x2 pk = { (_Float16)h, (_Float16)hn };
    return __builtin_bit_cast(unsigned, pk);
#endif
}

__global__ __launch_bounds__(64, 1)
void lstm_wave_scan(const float* __restrict__ x,
                    const float* __restrict__ W_ih,
                    const float* __restrict__ W_hh,
                    const float* __restrict__ b_ih,
                    const float* __restrict__ b_hh,
                    const float* __restrict__ W_lin,
                    const float* __restrict__ b_lin,
                    float* __restrict__ out,
                    int T) {
    __shared__ float h_hist[CHUNK][65];   // row stride 65: epilogue conflict-free

    const int lane = threadIdx.x;
    const int j    = lane & 31;
    const int half = lane >> 5;
    const int b    = blockIdx.x;

    const int row1 = j + (half << 5);         // A: i-row j     B: f-row 32+j
    const int row2 = 64 + j + (half << 5);    // A: g-row 64+j  B: o-row 96+j

    const float S1 = -1.44269504088896340736f;   // -log2(e)   (sigmoid rows)
    const float S2 = -2.88539008177792681472f;   // -2 log2(e) (tanh row)
    const float sc2 = half ? S1 : S2;            // row2: A is tanh, B is sigmoid

#ifdef HAVE_FDOT2
    // Pre-scaled f16-packed weights: w[m] = {W[row][2m], W[row][2m+1]} * scale
    f16x2 w1[16], w2[16];
#pragma unroll
    for (int m = 0; m < 16; ++m) {
        w1[m] = { (_Float16)(W_hh[row1 * HID + 2*m]     * S1),
                  (_Float16)(W_hh[row1 * HID + 2*m + 1] * S1) };
        w2[m] = { (_Float16)(W_hh[row2 * HID + 2*m]     * sc2),
                  (_Float16)(W_hh[row2 * HID + 2*m + 1] * sc2) };
    }
#else
    // f32 fallback: round-4 matvec (verified at 3276 us).
    f2 w1[16], w2[16];
#pragma unroll
    for (int m = 0; m < 16; ++m) {
        w1[m] = { W_hh[row1 * HID + 2*m] * S1,  W_hh[row1 * HID + 2*m + 1] * S1  };
        w2[m] = { W_hh[row2 * HID + 2*m] * sc2, W_hh[row2 * HID + 2*m + 1] * sc2 };
    }
#endif
    const float wih1 = W_ih[row1] * S1,  bb1 = (b_ih[row1] + b_hh[row1]) * S1;
    const float wih2 = W_ih[row2] * sc2, bb2 = (b_ih[row2] + b_hh[row2]) * sc2;

    // act2(v) = pb * rcp(1 + exp2(v)) + pc : A-lanes tanh (g), B-lanes sigmoid (o)
    const float pb = half ? 1.0f : 2.0f;
    const float pc = half ? 0.0f : -1.0f;

    const float blin = b_lin[0];

    float c = 0.0f;          // B-lanes: cell state
    float h = 0.0f;          // B-lanes: hidden state h_{t-1}
    unsigned hpk = 0;        // packed f16 pair {h[2m],h[2m+1]} at B-even lanes

    const float* xb = x   + (size_t)b * T;
    float*       ob = out + (size_t)b * T;

    float xv = xb[j];

    for (int t0 = 0; t0 < T; t0 += CHUNK) {
        int t0n = t0 + CHUNK; if (t0n >= T) t0n = 0;
        float xv_next = xb[t0n + j];

#pragma unroll 8
        for (int tt = 0; tt < CHUNK; ++tt) {
            const float sx = rl(xv, tt);  // wave-uniform x_t (off the h-chain)

            // 4-way split accumulators; x/bias folded into partial 0.
            float a1p0 = __builtin_fmaf(sx, wih1, bb1), a1p1 = 0.f, a1p2 = 0.f, a1p3 = 0.f;
            float a2p0 = __builtin_fmaf(sx, wih2, bb2), a2p1 = 0.f, a2p2 = 0.f, a2p3 = 0.f;

#ifdef HAVE_FDOT2
            // 16 readlanes of packed f16 pairs; each feeds 2 dot2s (1 SGPR operand).
#pragma unroll
            for (int m = 0; m < 16; ++m) {
                const unsigned s = rlu(hpk, 32 + 2*m);
                const f16x2 hb = __builtin_bit_cast(f16x2, s);
                if ((m & 3) == 0)      { a1p0 = __builtin_amdgcn_fdot2(w1[m], hb, a1p0, false);
                                         a2p0 = __builtin_amdgcn_fdot2(w2[m], hb, a2p0, false); }
                else if ((m & 3) == 1) { a1p1 = __builtin_amdgcn_fdot2(w1[m], hb, a1p1, false);
                                         a2p1 = __builtin_amdgcn_fdot2(w2[m], hb, a2p1, false); }
                else if ((m & 3) == 2) { a1p2 = __builtin_amdgcn_fdot2(w1[m], hb, a1p2, false);
                                         a2p2 = __builtin_amdgcn_fdot2(w2[m], hb, a2p2, false); }
                else                   { a1p3 = __builtin_amdgcn_fdot2(w1[m], hb, a1p3, false);
                                         a2p3 = __builtin_amdgcn_fdot2(w2[m], hb, a2p3, false); }
            }
#else
            // r4-style fallback matvec (f2 accumulators, f32 readlanes).
            {
                f2 A1 = { a1p0, a1p1 }, A2 = { a2p0, a2p1 };
#pragma unroll
                for (int m = 0; m < 16; ++m) {
                    f2 hm = { rl(h, 32 + 2*m), rl(h, 32 + 2*m + 1) };
                    A1 = __builtin_elementwise_fma(w1[m], hm, A1);
                    A2 = __builtin_elementwise_fma(w2[m], hm, A2);
                }
                a1p0 = A1.x; a1p1 = A1.y; a1p2 = 0.f; a1p3 = 0.f;
                a2p0 = A2.x; a2p1 = A2.y; a2p2 = 0.f; a2p3 = 0.f;
            }
#endif
            const float g1 = (a1p0 + a1p1) + (a1p2 + a1p3);  // A: i-pre  B: f-pre
            const float g2 = (a2p0 + a2p1) + (a2p2 + a2p3);  // A: g-pre  B: o-pre

            // Activations (weights pre-scaled: rcp(1+exp2(v)) directly).
            const float a1 = __builtin_amdgcn_rcpf(1.0f + __builtin_amdgcn_exp2f(g1));
            const float a2 = __builtin_fmaf(pb,
                               __builtin_amdgcn_rcpf(1.0f + __builtin_amdgcn_exp2f(g2)), pc);

            const float p = a1 * a2;            // A: i*g     B: f*o
            const float q = cross_half(p);      // A: f*o     B: i*g

            c = __builtin_fmaf(a1, c, q);       // B: f*c + i*g
            const float e = __builtin_amdgcn_exp2f(c * S2);
            const float th = __builtin_fmaf(2.0f, __builtin_amdgcn_rcpf(1.0f + e), -1.0f);
            h = a2 * th;                        // B: o*tanh(c)

            hpk = pack_pair_f16(h);             // next step's broadcast payload
            h_hist[tt][lane] = h;               // cols 32..63 hold the real h
        }

        // ---- epilogue: out[b][t0+t'] = x + W_lin . h_t' + b_lin, t' = j
        {
            float facc = 0.0f;
#pragma unroll
            for (int k = 0; k < 32; ++k)
                facc = __builtin_fmaf(W_lin[k], h_hist[j][32 + k], facc);
            if (half == 0)
                ob[t0 + j] = xv + facc + blin;
        }

        xv = xv_next;
    }
}

extern "C" void kernel_launch(void* const* d_in, const int* in_sizes, int n_in,
                              void* d_out, int out_size, void* d_ws, size_t ws_size,
                              hipStream_t stream) {
    const float* x     = (const float*)d_in[0];
    const float* W_ih  = (const float*)d_in[1];
    const float* W_hh  = (const float*)d_in[2];
    const float* b_ih  = (const float*)d_in[3];
    const float* b_hh  = (const float*)d_in[4];
    const float* W_lin = (const float*)d_in[5];
    const float* b_lin = (const float*)d_in[6];
    float* out = (float*)d_out;

    const int B = 64;
    const int T = in_sizes[0] / B;   // 16384

    dim3 grid(B);                    // one wave per batch
    dim3 block(64);
    lstm_wave_scan<<<grid, block, 0, stream>>>(x, W_ih, W_hh, b_ih, b_hh,
                                               W_lin, b_lin, out, T);
}

// Round 9
// 3363.364 us; speedup vs baseline: 1.9875x; 1.1034x over previous
//
#include <hip/hip_runtime.h>

// LSTM scan, B=64, T=16384, H=32, I=O=1, fp32 in/out.
// ONE WAVE PER BATCH (64 blocks x 64 threads). Latency-bound serial scan:
// wall time = T x per-step dependence chain of one wave.
//
// Round-9 = round-4 base (3276 us, best verified) + three chain cuts:
//   1. accumulator chain depth 16 -> 8 (two f2 accumulators per gate).
//   2. weights/biases pre-scaled by -log2(e) / -2log2(e): no multiply
//      before the gate exp2s.
//   3. S2 folded into the g-gate output (A-half pb=2*S2, pc=-S2), cell
//      state kept as c' = S2*c: kills the c*S2 multiply before tanh's exp2.
//
// Hard lessons encoded:
//   r1/r5: DS-pipe ops (shfl/bpermute) on the chain are poison (~100+ cyc).
//   r3:    permlane32_swap ONLY via the builtin (hazard wait-states).
//   r6:    readlane results must NOT be consumed by SALU ops.
//   r8:    pack-on-chain (DPP+pkrtz before readlane) costs more than it
//          saves; readlane count is NOT the dominant term. f32 stays.
//
// Lane mapping: j = lane&31, half = lane>>5.
//   A-lanes (half=0): gates i (row j)    and g (row 64+j)
//   B-lanes (half=1): gates f (row 32+j) and o (row 96+j)
// c',h valid in B-lanes; A-lanes compute bounded garbage (i-contraction).

#define HID 32
#define CHUNK 32

typedef float f2 __attribute__((ext_vector_type(2)));
typedef unsigned int u32x2 __attribute__((ext_vector_type(2)));

#if defined(__has_builtin)
#if __has_builtin(__builtin_amdgcn_permlane32_swap)
#define HAVE_PLSWAP 1
#endif
#endif

__device__ __forceinline__ float rl(float v, int lane) {
    return __int_as_float(__builtin_amdgcn_readlane(__float_as_int(v), lane));
}

// Exchange p across wave halves (exact, orientation-independent, VALU-only).
__device__ __forceinline__ float cross_half(float p) {
#ifdef HAVE_PLSWAP
    const unsigned pu = __float_as_uint(p);
    u32x2 r = __builtin_amdgcn_permlane32_swap(pu, pu, false, false);
    return __uint_as_float(r[0] ^ r[1] ^ pu);
#else
    return __shfl_xor(p, 32, 64);
#endif
}

__global__ __launch_bounds__(64, 1)
void lstm_wave_scan(const float* __restrict__ x,
                    const float* __restrict__ W_ih,
                    const float* __restrict__ W_hh,
                    const float* __restrict__ b_ih,
                    const float* __restrict__ b_hh,
                    const float* __restrict__ W_lin,
                    const float* __restrict__ b_lin,
                    float* __restrict__ out,
                    int T) {
    __shared__ float h_hist[CHUNK][65];   // row stride 65: epilogue conflict-free

    const int lane = threadIdx.x;
    const int j    = lane & 31;
    const int half = lane >> 5;
    const int b    = blockIdx.x;

    const int row1 = j + (half << 5);         // A: i-row j     B: f-row 32+j
    const int row2 = 64 + j + (half << 5);    // A: g-row 64+j  B: o-row 96+j

    const float S1 = -1.44269504088896340736f;   // -log2(e)   (sigmoid rows)
    const float S2 = -2.88539008177792681472f;   // -2 log2(e) (tanh row)
    const float sc2 = half ? S1 : S2;            // row2: A is tanh(g), B is sigmoid(o)

    // Pre-scaled f32 weights (f2-packed for v_pk_fma_f32).
    f2 w1[16], w2[16];
#pragma unroll
    for (int m = 0; m < 16; ++m) {
        w1[m] = { W_hh[row1 * HID + 2*m] * S1,  W_hh[row1 * HID + 2*m + 1] * S1  };
        w2[m] = { W_hh[row2 * HID + 2*m] * sc2, W_hh[row2 * HID + 2*m + 1] * sc2 };
    }
    const float wih1 = W_ih[row1] * S1,  bb1 = (b_ih[row1] + b_hh[row1]) * S1;
    const float wih2 = W_ih[row2] * sc2, bb2 = (b_ih[row2] + b_hh[row2]) * sc2;

    // act2(v) = pb * rcp(1 + exp2(v)) + pc
    //   A-lanes: S2-scaled tanh -> a2 = S2*g   (pb = 2*S2, pc = -S2)
    //   B-lanes: sigmoid        -> a2 = o      (pb = 1,    pc = 0)
    // Then q (into B) = i * (S2*g) = S2*(i*g), and cell state is c' = S2*c,
    // so tanh(c) = 2*rcp(1+exp2(c')) - 1 with NO multiply before exp2.
    const float pb = half ? 1.0f : 2.0f * S2;
    const float pc = half ? 0.0f : -S2;

    const float blin = b_lin[0];

    float c = 0.0f;     // B-lanes: scaled cell state c' = S2*c
    float h = 0.0f;     // B-lanes: hidden state h_{t-1}

    const float* xb = x   + (size_t)b * T;
    float*       ob = out + (size_t)b * T;

    float xv = xb[j];

    for (int t0 = 0; t0 < T; t0 += CHUNK) {
        int t0n = t0 + CHUNK; if (t0n >= T) t0n = 0;
        float xv_next = xb[t0n + j];

#pragma unroll 8
        for (int tt = 0; tt < CHUNK; ++tt) {
            const float sx = rl(xv, tt);  // wave-uniform x_t (off the h-chain)

            // Two f2 accumulators per gate: dependent chain depth 8, not 16.
            f2 A1a = { __builtin_fmaf(sx, wih1, bb1), 0.0f };
            f2 A1b = { 0.0f, 0.0f };
            f2 A2a = { __builtin_fmaf(sx, wih2, bb2), 0.0f };
            f2 A2b = { 0.0f, 0.0f };

#pragma unroll
            for (int m = 0; m < 8; ++m) {
                f2 hm0 = { rl(h, 32 + 4*m),     rl(h, 32 + 4*m + 1) };
                f2 hm1 = { rl(h, 32 + 4*m + 2), rl(h, 32 + 4*m + 3) };
                A1a = __builtin_elementwise_fma(w1[2*m],     hm0, A1a);
                A2a = __builtin_elementwise_fma(w2[2*m],     hm0, A2a);
                A1b = __builtin_elementwise_fma(w1[2*m + 1], hm1, A1b);
                A2b = __builtin_elementwise_fma(w2[2*m + 1], hm1, A2b);
            }
            const float g1 = (A1a.x + A1b.x) + (A1a.y + A1b.y);  // A: i-pre  B: f-pre
            const float g2 = (A2a.x + A2b.x) + (A2a.y + A2b.y);  // A: g-pre  B: o-pre

            // Activations (pre-scaled: rcp(1+exp2(v)) directly).
            const float a1 = __builtin_amdgcn_rcpf(1.0f + __builtin_amdgcn_exp2f(g1));
            const float a2 = __builtin_fmaf(pb,
                               __builtin_amdgcn_rcpf(1.0f + __builtin_amdgcn_exp2f(g2)), pc);

            const float p = a1 * a2;            // A: i*(S2*g)   B: f*o
            const float q = cross_half(p);      // A: f*o        B: S2*(i*g)

            c = __builtin_fmaf(a1, c, q);       // B: c' = f*c' + S2*i*g
            const float e  = __builtin_amdgcn_exp2f(c);              // no multiply!
            const float th = __builtin_fmaf(2.0f, __builtin_amdgcn_rcpf(1.0f + e), -1.0f);
            h = a2 * th;                        // B: o * tanh(c)

            h_hist[tt][lane] = h;               // cols 32..63 hold the real h
        }

        // ---- epilogue: out[b][t0+t'] = x + W_lin . h_t' + b_lin, t' = j
        {
            float facc = 0.0f;
#pragma unroll
            for (int k = 0; k < 32; ++k)
                facc = __builtin_fmaf(W_lin[k], h_hist[j][32 + k], facc);
            if (half == 0)
                ob[t0 + j] = xv + facc + blin;
        }

        xv = xv_next;
    }
}

extern "C" void kernel_launch(void* const* d_in, const int* in_sizes, int n_in,
                              void* d_out, int out_size, void* d_ws, size_t ws_size,
                              hipStream_t stream) {
    const float* x     = (const float*)d_in[0];
    const float* W_ih  = (const float*)d_in[1];
    const float* W_hh  = (const float*)d_in[2];
    const float* b_ih  = (const float*)d_in[3];
    const float* b_hh  = (const float*)d_in[4];
    const float* W_lin = (const float*)d_in[5];
    const float* b_lin = (const float*)d_in[6];
    float* out = (float*)d_out;

    const int B = 64;
    const int T = in_sizes[0] / B;   // 16384

    dim3 grid(B);                    // one wave per batch
    dim3 block(64);
    lstm_wave_scan<<<grid, block, 0, stream>>>(x, W_ih, W_hh, b_ih, b_hh,
                                               W_lin, b_lin, out, T);
}